// Round 15
// baseline (171.511 us; speedup 1.0000x reference)
//
#include <hip/hip_runtime.h>
#include <math.h>

#define FFT_N   4096
#define THREADS 256
#define PADN    4352            // max pad4 index 4347
#define GRID    512             // persistent: 2 blocks/CU (LDS-bound)
#define NPAIRS  8192
#define ITERS   (NPAIRS / GRID) // 16
#define LDS_BYTES ((8192 + 2 * PADN) * 4)   // S(32KB) + re/im work (34816B) = 67584

// R9 champion work-buffer layout: additive pad pad4(i) = i + 4*(i>>6).
//  A (i=t+256k):    base [t+4*(t>>6)] + 272k        linear -> ds imm, 2-way banks
//  B (i=256a+j+16k): base [272a+j] + 16k+4*(k>>2)   linear -> ds imm, 2-way banks
//  C (i=16t+n):     base [16t+4*(t>>2)] + n         contiguous 16B-aligned -> b128
// R15: persistent blocks; next pair's input DMA'd into LDS staging buffer S
// via global_load_lds(16B) issued right after the A->B barrier, overlapping
// the whole B/C/B' middle. Stage A reads S at stride 256 (2-way banks, all
// offsets immediate). Stores moved after the W-protect barrier so they
// overlap the next iteration's stage A. VGPR stays at R9 level (no register
// prefetch - that was R13's spill disaster).

#define REV(r) ((((r) & 3) << 2) | ((r) >> 2))

typedef const __attribute__((address_space(1))) unsigned int* gas_t;
typedef __attribute__((address_space(3))) unsigned int* las_t;

// gperm[16t + r] = G at local position 16t + REV(r),
// G(p) = ((W[k]+W[(N-k)%N])/2 + 1)/N, k = 3-digit base-16 reversal of p.
__global__ void setup_g_kernel(const float* __restrict__ fw, float* __restrict__ gperm) {
    int p = blockIdx.x * blockDim.x + threadIdx.x;
    if (p >= FFT_N) return;
    int r = p & 15;
    int local = (p & ~15) | REV(r);
    unsigned k = ((local & 15u) << 8) | ((unsigned)local & 0xF0u) | ((unsigned)local >> 8);
    float wk  = fw[k];
    float wnk = fw[(FFT_N - k) & (FFT_N - 1)];
    gperm[p] = (0.5f * (wk + wnk) + 1.0f) * (1.0f / (float)FFT_N);
}

__device__ __forceinline__ void cmul(float& xr, float& xi, float c, float s) {
    float tv = xr; xr = tv * c - xi * s; xi = tv * s + xi * c;
}

__device__ __forceinline__ void bfly4_f(float& ar, float& ai, float& br, float& bi,
                                        float& cr, float& ci, float& dr, float& di) {
    float t0r = ar + cr, t0i = ai + ci;
    float t1r = ar - cr, t1i = ai - ci;
    float t2r = br + dr, t2i = bi + di;
    float t3r = br - dr, t3i = bi - di;
    ar = t0r + t2r; ai = t0i + t2i;
    br = t1r + t3i; bi = t1i - t3r;
    cr = t0r - t2r; ci = t0i - t2i;
    dr = t1r - t3i; di = t1i + t3r;
}
__device__ __forceinline__ void bfly4_i(float& ar, float& ai, float& br, float& bi,
                                        float& cr, float& ci, float& dr, float& di) {
    float t0r = ar + cr, t0i = ai + ci;
    float t1r = ar - cr, t1i = ai - ci;
    float t2r = br + dr, t2i = bi + di;
    float t3r = br - dr, t3i = bi - di;
    ar = t0r + t2r; ai = t0i + t2i;
    br = t1r - t3i; bi = t1i + t3r;
    cr = t0r - t2r; ci = t0i - t2i;
    dr = t1r + t3i; di = t1i - t3r;
}

// In-place forward DFT16 (DIF). Output: slot r holds X[REV(r)].
__device__ __forceinline__ void dft16_f(float xr[16], float xi[16]) {
    const float C1 = 0.9238795325112867f;
    const float S1 = 0.3826834323650898f;
    const float H  = 0.7071067811865476f;
    #pragma unroll
    for (int m = 0; m < 4; ++m)
        bfly4_f(xr[m],xi[m], xr[m+4],xi[m+4], xr[m+8],xi[m+8], xr[m+12],xi[m+12]);
    cmul(xr[5],  xi[5],   C1, -S1);
    cmul(xr[9],  xi[9],    H,  -H);
    cmul(xr[13], xi[13],  S1, -C1);
    cmul(xr[6],  xi[6],    H,  -H);
    cmul(xr[10], xi[10], 0.f, -1.f);
    cmul(xr[14], xi[14],  -H,  -H);
    cmul(xr[7],  xi[7],   S1, -C1);
    cmul(xr[11], xi[11],  -H,  -H);
    cmul(xr[15], xi[15], -C1,  S1);
    #pragma unroll
    for (int g = 0; g < 4; ++g)
        bfly4_f(xr[4*g],xi[4*g], xr[4*g+1],xi[4*g+1], xr[4*g+2],xi[4*g+2], xr[4*g+3],xi[4*g+3]);
}

// In-place inverse DFT16 (unnormalized). Input: slot r holds X[REV(r)].
__device__ __forceinline__ void idft16(float xr[16], float xi[16]) {
    const float C1 = 0.9238795325112867f;
    const float S1 = 0.3826834323650898f;
    const float H  = 0.7071067811865476f;
    #pragma unroll
    for (int g = 0; g < 4; ++g)
        bfly4_i(xr[4*g],xi[4*g], xr[4*g+1],xi[4*g+1], xr[4*g+2],xi[4*g+2], xr[4*g+3],xi[4*g+3]);
    cmul(xr[5],  xi[5],   C1,  S1);
    cmul(xr[9],  xi[9],    H,   H);
    cmul(xr[13], xi[13],  S1,  C1);
    cmul(xr[6],  xi[6],    H,   H);
    cmul(xr[10], xi[10], 0.f, 1.f);
    cmul(xr[14], xi[14],  -H,   H);
    cmul(xr[7],  xi[7],   S1,  C1);
    cmul(xr[11], xi[11],  -H,   H);
    cmul(xr[15], xi[15], -C1, -S1);
    #pragma unroll
    for (int m = 0; m < 4; ++m)
        bfly4_i(xr[m],xi[m], xr[m+4],xi[m+4], xr[m+8],xi[m+8], xr[m+12],xi[m+12]);
}

// apply w^{REV(r)} to slot r; binary-power chain, dependency depth ~5.
__device__ __forceinline__ void twiddle_rev(float xr[16], float xi[16], float ang) {
    float s1, c1; __sincosf(ang, &s1, &c1);
    float c2 = c1*c1 - s1*s1, s2 = 2.f*c1*s1;
    float c3 = c2*c1 - s2*s1, s3 = c2*s1 + s2*c1;
    float c4 = c2*c2 - s2*s2, s4 = 2.f*c2*s2;
    cmul(xr[4],  xi[4],  c1, s1);
    cmul(xr[8],  xi[8],  c2, s2);
    cmul(xr[12], xi[12], c3, s3);
    float bc = c4, bs = s4;
    #pragma unroll
    for (int q = 1; q < 4; ++q) {
        cmul(xr[q], xi[q], bc, bs);
        { float ec = bc*c1 - bs*s1, es = bc*s1 + bs*c1; cmul(xr[4+q],  xi[4+q],  ec, es); }
        { float ec = bc*c2 - bs*s2, es = bc*s2 + bs*c2; cmul(xr[8+q],  xi[8+q],  ec, es); }
        { float ec = bc*c3 - bs*s3, es = bc*s3 + bs*c3; cmul(xr[12+q], xi[12+q], ec, es); }
        if (q < 3) { float nb = bc*c4 - bs*s4; bs = bc*s4 + bs*c4; bc = nb; }
    }
}

__global__ __launch_bounds__(THREADS) void fourier_fft_kernel(
    const float* __restrict__ in, const float* __restrict__ gperm,
    const float* __restrict__ lw, float* __restrict__ out)
{
    extern __shared__ __align__(16) float lds[];
    float* S  = lds;                 // 8192 floats: staged input, natural order
    float* re = lds + 8192;          // PADN floats
    float* im = lds + 8192 + PADN;   // PADN floats

    const int t = threadIdx.x;
    const int wv = t >> 6, ln = t & 63;

    const float CFA = -6.28318530717958647692f / 4096.0f;
    const float CFB = -6.28318530717958647692f / 256.0f;

    const int baseA = t + 4 * (t >> 6);                        // + 272k
    const int baseB = 272 * (t >> 4) + (t & 15);               // + 16k + 4*(k>>2)
    const int baseC = 16 * t + 4 * (t >> 2);                   // + n (16B-aligned)
    const int jb = t & 15;
    const float angA =  CFA * (float)t;
    const float angB =  CFB * (float)jb;

    float xr[16], xi[16];
    long long pair = blockIdx.x;

    // prologue: DMA pair 0's input (both rows, 32 KB) into S
    {
        const float* g0 = in + pair * (2LL * FFT_N);
        #pragma unroll
        for (int q = 0; q < 8; ++q) {
            const int chunk = wv * 8 + q;                       // 0..31, wave-uniform
            __builtin_amdgcn_global_load_lds(
                (gas_t)(g0 + chunk * 256 + ln * 4),
                (las_t)(S + chunk * 256), 16, 0, 0);
        }
    }
    __syncthreads();   // drains vmcnt -> staged data visible

    for (int it = 0; it < ITERS; ++it) {
        // ---- stage A: read S (stride-256 b32, 2-way banks, imm offsets)
        #pragma unroll
        for (int n = 0; n < 16; ++n) {
            xr[n] = S[t + 256*n];
            xi[n] = S[4096 + t + 256*n];
        }
        dft16_f(xr, xi);
        twiddle_rev(xr, xi, angA);
        #pragma unroll
        for (int k = 0; k < 16; ++k) {
            re[baseA + 272*k] = xr[REV(k)];
            im[baseA + 272*k] = xi[REV(k)];
        }
        __syncthreads();   // barrier1: all S-reads done, W(A) ready

        // ---- issue DMA of next pair into S; overlaps B/C/B' compute
        if (it + 1 < ITERS) {
            const float* gn = in + (pair + GRID) * (2LL * FFT_N);
            #pragma unroll
            for (int q = 0; q < 8; ++q) {
                const int chunk = wv * 8 + q;
                __builtin_amdgcn_global_load_lds(
                    (gas_t)(gn + chunk * 256 + ln * 4),
                    (las_t)(S + chunk * 256), 16, 0, 0);
            }
        }

        // ---- forward stage B (intra-wave exchange, no barrier needed after)
        #pragma unroll
        for (int n = 0; n < 16; ++n) {
            int s = baseB + 16*n + 4*(n>>2);
            xr[n] = re[s]; xi[n] = im[s];
        }
        dft16_f(xr, xi);
        twiddle_rev(xr, xi, angB);
        #pragma unroll
        for (int k = 0; k < 16; ++k) {
            int s = baseB + 16*k + 4*(k>>2);
            re[s] = xr[REV(k)]; im[s] = xi[REV(k)];
        }

        // ---- stage C + G + C' (registers; b128 LDS both sides)
        #pragma unroll
        for (int q = 0; q < 4; ++q) {
            float4 vr = *(const float4*)&re[baseC + 4*q];
            float4 vi = *(const float4*)&im[baseC + 4*q];
            xr[4*q+0] = vr.x; xr[4*q+1] = vr.y; xr[4*q+2] = vr.z; xr[4*q+3] = vr.w;
            xi[4*q+0] = vi.x; xi[4*q+1] = vi.y; xi[4*q+2] = vi.z; xi[4*q+3] = vi.w;
        }
        dft16_f(xr, xi);
        {
            const float4* gp = (const float4*)(gperm + 16*t);
            #pragma unroll
            for (int q = 0; q < 4; ++q) {
                float4 g = gp[q];
                xr[4*q+0] *= g.x; xi[4*q+0] *= g.x;
                xr[4*q+1] *= g.y; xi[4*q+1] *= g.y;
                xr[4*q+2] *= g.z; xi[4*q+2] *= g.z;
                xr[4*q+3] *= g.w; xi[4*q+3] *= g.w;
            }
        }
        idft16(xr, xi);
        #pragma unroll
        for (int q = 0; q < 4; ++q) {
            *(float4*)&re[baseC + 4*q] = make_float4(xr[4*q+0], xr[4*q+1], xr[4*q+2], xr[4*q+3]);
            *(float4*)&im[baseC + 4*q] = make_float4(xi[4*q+0], xi[4*q+1], xi[4*q+2], xi[4*q+3]);
        }

        // ---- inverse stage B' (intra-wave)
        #pragma unroll
        for (int k = 0; k < 16; ++k) {
            int s = baseB + 16*k + 4*(k>>2);
            xr[REV(k)] = re[s]; xi[REV(k)] = im[s];
        }
        twiddle_rev(xr, xi, -angB);
        idft16(xr, xi);
        #pragma unroll
        for (int n = 0; n < 16; ++n) {
            int s = baseB + 16*n + 4*(n>>2);
            re[s] = xr[n]; xi[n] = xi[n]; im[s] = xi[n];
        }
        __syncthreads();   // barrier2: W(B') ready for A' (also drains DMA)

        // ---- inverse stage A'
        #pragma unroll
        for (int k = 0; k < 16; ++k) {
            xr[REV(k)] = re[baseA + 272*k];
            xi[REV(k)] = im[baseA + 272*k];
        }
        twiddle_rev(xr, xi, -angA);
        idft16(xr, xi);
        __syncthreads();   // barrier3: all A'-reads of W done; W free for next A

        // ---- epilogue stores (after barrier3 -> overlap next stage A)
        {
            float* o0 = out + pair * (2LL * FFT_N);
            #pragma unroll
            for (int n = 0; n < 16; ++n) {
                int i = t + 256*n;
                float l = lw[i];
                o0[i]         = fmaxf(xr[n]*l, 0.0f);
                o0[FFT_N + i] = fmaxf(xi[n]*l, 0.0f);
            }
        }
        pair += GRID;
    }
}

extern "C" void kernel_launch(void* const* d_in, const int* in_sizes, int n_in,
                              void* d_out, int out_size, void* d_ws, size_t ws_size,
                              hipStream_t stream) {
    const float* inputs = (const float*)d_in[0];
    const float* fw     = (const float*)d_in[1];
    const float* lw     = (const float*)d_in[2];
    float* out   = (float*)d_out;
    float* gperm = (float*)d_ws;   // 4096 floats = 16 KB scratch

    // allow >64KB dynamic LDS (gfx950 has 160 KB/CU); idempotent, non-stream op
    (void)hipFuncSetAttribute((const void*)fourier_fft_kernel,
                              hipFuncAttributeMaxDynamicSharedMemorySize, LDS_BYTES);

    hipLaunchKernelGGL(setup_g_kernel, dim3(FFT_N / THREADS), dim3(THREADS), 0, stream,
                       fw, gperm);

    hipLaunchKernelGGL(fourier_fft_kernel, dim3(GRID), dim3(THREADS), LDS_BYTES, stream,
                       inputs, gperm, lw, out);
}

// Round 16
// 167.634 us; speedup vs baseline: 1.0231x; 1.0231x over previous
//
#include <hip/hip_runtime.h>
#include <math.h>

#define FFT_N   4096
#define THREADS 256
#define GRID    512             // persistent: 2 blocks/CU
#define NPAIRS  8192
#define ITERS   (NPAIRS / GRID) // 16

// R16: R15's DMA-prefetch structure with total LDS = EXACTLY 64 KB so two
// blocks co-reside per CU (R15's 67.6 KB forced 1 block/CU -> 171 us).
//   S  (8192 floats, 32 KB): staged input, natural order, written by
//       global_load_lds(16B); reads are stride-256 b32 -> bank t&31, 2-way.
//   W  (re/im, 4096 floats each, 32 KB): XOR swizzle swz(i)=i^((i>>5)&31),
//       zero padding; proven <=2-way on A (t+256k), B (256a+j+16k),
//       C (16t+n) patterns (R7 analysis, re-verified).
// DMA of next pair issued right after barrier1 (all S-reads done), flies
// through the whole B/C/B' middle, drained by barrier2's implicit vmcnt(0).
// Stores after barrier3 so they overlap the next iteration's stage A.

#define REV(r) ((((r) & 3) << 2) | ((r) >> 2))

__device__ __forceinline__ int swz(int i) { return i ^ ((i >> 5) & 31); }

typedef const __attribute__((address_space(1))) unsigned int* gas_t;
typedef __attribute__((address_space(3))) unsigned int* las_t;

// gperm[16t + r] = G at local position 16t + REV(r),
// G(p) = ((W[k]+W[(N-k)%N])/2 + 1)/N, k = 3-digit base-16 reversal of p.
__global__ void setup_g_kernel(const float* __restrict__ fw, float* __restrict__ gperm) {
    int p = blockIdx.x * blockDim.x + threadIdx.x;
    if (p >= FFT_N) return;
    int r = p & 15;
    int local = (p & ~15) | REV(r);
    unsigned k = ((local & 15u) << 8) | ((unsigned)local & 0xF0u) | ((unsigned)local >> 8);
    float wk  = fw[k];
    float wnk = fw[(FFT_N - k) & (FFT_N - 1)];
    gperm[p] = (0.5f * (wk + wnk) + 1.0f) * (1.0f / (float)FFT_N);
}

__device__ __forceinline__ void cmul(float& xr, float& xi, float c, float s) {
    float tv = xr; xr = tv * c - xi * s; xi = tv * s + xi * c;
}

__device__ __forceinline__ void bfly4_f(float& ar, float& ai, float& br, float& bi,
                                        float& cr, float& ci, float& dr, float& di) {
    float t0r = ar + cr, t0i = ai + ci;
    float t1r = ar - cr, t1i = ai - ci;
    float t2r = br + dr, t2i = bi + di;
    float t3r = br - dr, t3i = bi - di;
    ar = t0r + t2r; ai = t0i + t2i;
    br = t1r + t3i; bi = t1i - t3r;
    cr = t0r - t2r; ci = t0i - t2i;
    dr = t1r - t3i; di = t1i + t3r;
}
__device__ __forceinline__ void bfly4_i(float& ar, float& ai, float& br, float& bi,
                                        float& cr, float& ci, float& dr, float& di) {
    float t0r = ar + cr, t0i = ai + ci;
    float t1r = ar - cr, t1i = ai - ci;
    float t2r = br + dr, t2i = bi + di;
    float t3r = br - dr, t3i = bi - di;
    ar = t0r + t2r; ai = t0i + t2i;
    br = t1r - t3i; bi = t1i + t3r;
    cr = t0r - t2r; ci = t0i - t2i;
    dr = t1r + t3i; di = t1i - t3r;
}

// In-place forward DFT16 (DIF). Output: slot r holds X[REV(r)].
__device__ __forceinline__ void dft16_f(float xr[16], float xi[16]) {
    const float C1 = 0.9238795325112867f;
    const float S1 = 0.3826834323650898f;
    const float H  = 0.7071067811865476f;
    #pragma unroll
    for (int m = 0; m < 4; ++m)
        bfly4_f(xr[m],xi[m], xr[m+4],xi[m+4], xr[m+8],xi[m+8], xr[m+12],xi[m+12]);
    cmul(xr[5],  xi[5],   C1, -S1);
    cmul(xr[9],  xi[9],    H,  -H);
    cmul(xr[13], xi[13],  S1, -C1);
    cmul(xr[6],  xi[6],    H,  -H);
    cmul(xr[10], xi[10], 0.f, -1.f);
    cmul(xr[14], xi[14],  -H,  -H);
    cmul(xr[7],  xi[7],   S1, -C1);
    cmul(xr[11], xi[11],  -H,  -H);
    cmul(xr[15], xi[15], -C1,  S1);
    #pragma unroll
    for (int g = 0; g < 4; ++g)
        bfly4_f(xr[4*g],xi[4*g], xr[4*g+1],xi[4*g+1], xr[4*g+2],xi[4*g+2], xr[4*g+3],xi[4*g+3]);
}

// In-place inverse DFT16 (unnormalized). Input: slot r holds X[REV(r)].
__device__ __forceinline__ void idft16(float xr[16], float xi[16]) {
    const float C1 = 0.9238795325112867f;
    const float S1 = 0.3826834323650898f;
    const float H  = 0.7071067811865476f;
    #pragma unroll
    for (int g = 0; g < 4; ++g)
        bfly4_i(xr[4*g],xi[4*g], xr[4*g+1],xi[4*g+1], xr[4*g+2],xi[4*g+2], xr[4*g+3],xi[4*g+3]);
    cmul(xr[5],  xi[5],   C1,  S1);
    cmul(xr[9],  xi[9],    H,   H);
    cmul(xr[13], xi[13],  S1,  C1);
    cmul(xr[6],  xi[6],    H,   H);
    cmul(xr[10], xi[10], 0.f, 1.f);
    cmul(xr[14], xi[14],  -H,   H);
    cmul(xr[7],  xi[7],   S1,  C1);
    cmul(xr[11], xi[11],  -H,   H);
    cmul(xr[15], xi[15], -C1, -S1);
    #pragma unroll
    for (int m = 0; m < 4; ++m)
        bfly4_i(xr[m],xi[m], xr[m+4],xi[m+4], xr[m+8],xi[m+8], xr[m+12],xi[m+12]);
}

// apply w^{REV(r)} to slot r; binary-power chain, dependency depth ~5.
__device__ __forceinline__ void twiddle_rev(float xr[16], float xi[16], float ang) {
    float s1, c1; __sincosf(ang, &s1, &c1);
    float c2 = c1*c1 - s1*s1, s2 = 2.f*c1*s1;
    float c3 = c2*c1 - s2*s1, s3 = c2*s1 + s2*c1;
    float c4 = c2*c2 - s2*s2, s4 = 2.f*c2*s2;
    cmul(xr[4],  xi[4],  c1, s1);
    cmul(xr[8],  xi[8],  c2, s2);
    cmul(xr[12], xi[12], c3, s3);
    float bc = c4, bs = s4;
    #pragma unroll
    for (int q = 1; q < 4; ++q) {
        cmul(xr[q], xi[q], bc, bs);
        { float ec = bc*c1 - bs*s1, es = bc*s1 + bs*c1; cmul(xr[4+q],  xi[4+q],  ec, es); }
        { float ec = bc*c2 - bs*s2, es = bc*s2 + bs*c2; cmul(xr[8+q],  xi[8+q],  ec, es); }
        { float ec = bc*c3 - bs*s3, es = bc*s3 + bs*c3; cmul(xr[12+q], xi[12+q], ec, es); }
        if (q < 3) { float nb = bc*c4 - bs*s4; bs = bc*s4 + bs*c4; bc = nb; }
    }
}

__global__ __launch_bounds__(THREADS) void fourier_fft_kernel(
    const float* __restrict__ in, const float* __restrict__ gperm,
    const float* __restrict__ lw, float* __restrict__ out)
{
    __shared__ __align__(16) float S[8192];    // 32 KB staging
    __shared__ float re[FFT_N];                // 16 KB
    __shared__ float im[FFT_N];                // 16 KB  -> total exactly 64 KB

    const int t = threadIdx.x;
    const int wv = t >> 6, ln = t & 63;

    const float CFA = -6.28318530717958647692f / 4096.0f;
    const float CFB = -6.28318530717958647692f / 256.0f;

    const int jb = t & 15;
    const float angA = CFA * (float)t;
    const float angB = CFB * (float)jb;
    const int baseB0 = (t >> 4) * 256 + jb;    // B-pattern base (pre-swizzle)

    float xr[16], xi[16];
    long long pair = blockIdx.x;

    // prologue: DMA pair 0's input (both rows, 32 KB) into S
    {
        const float* g0 = in + pair * (2LL * FFT_N);
        #pragma unroll
        for (int q = 0; q < 8; ++q) {
            const int chunk = wv * 8 + q;                       // 0..31, wave-uniform
            __builtin_amdgcn_global_load_lds(
                (gas_t)(g0 + chunk * 256 + ln * 4),
                (las_t)(S + chunk * 256), 16, 0, 0);
        }
    }
    __syncthreads();

    for (int it = 0; it < ITERS; ++it) {
        // ---- stage A: read S (stride-256 b32, 2-way banks)
        #pragma unroll
        for (int n = 0; n < 16; ++n) {
            xr[n] = S[t + 256*n];
            xi[n] = S[4096 + t + 256*n];
        }
        dft16_f(xr, xi);
        twiddle_rev(xr, xi, angA);
        #pragma unroll
        for (int k = 0; k < 16; ++k) {
            int s = swz(t + 256*k);
            re[s] = xr[REV(k)]; im[s] = xi[REV(k)];
        }
        __syncthreads();   // barrier1: all S-reads done, W(A) ready

        // ---- issue DMA of next pair into S; overlaps B/C/B' compute
        if (it + 1 < ITERS) {
            const float* gn = in + (pair + GRID) * (2LL * FFT_N);
            #pragma unroll
            for (int q = 0; q < 8; ++q) {
                const int chunk = wv * 8 + q;
                __builtin_amdgcn_global_load_lds(
                    (gas_t)(gn + chunk * 256 + ln * 4),
                    (las_t)(S + chunk * 256), 16, 0, 0);
            }
        }

        // ---- forward stage B (intra-wave exchange)
        #pragma unroll
        for (int n = 0; n < 16; ++n) {
            int s = swz(baseB0 + 16*n);
            xr[n] = re[s]; xi[n] = im[s];
        }
        dft16_f(xr, xi);
        twiddle_rev(xr, xi, angB);
        #pragma unroll
        for (int k = 0; k < 16; ++k) {
            int s = swz(baseB0 + 16*k);
            re[s] = xr[REV(k)]; im[s] = xi[REV(k)];
        }

        // ---- stage C + G + C' (registers; intra-wave LDS exchange)
        #pragma unroll
        for (int n = 0; n < 16; ++n) {
            int s = swz(16*t + n);
            xr[n] = re[s]; xi[n] = im[s];
        }
        dft16_f(xr, xi);
        {
            const float4* gp = (const float4*)(gperm + 16*t);   // REV-permuted
            #pragma unroll
            for (int q = 0; q < 4; ++q) {
                float4 g = gp[q];
                xr[4*q+0] *= g.x; xi[4*q+0] *= g.x;
                xr[4*q+1] *= g.y; xi[4*q+1] *= g.y;
                xr[4*q+2] *= g.z; xi[4*q+2] *= g.z;
                xr[4*q+3] *= g.w; xi[4*q+3] *= g.w;
            }
        }
        idft16(xr, xi);
        #pragma unroll
        for (int n = 0; n < 16; ++n) {
            int s = swz(16*t + n);
            re[s] = xr[n]; im[s] = xi[n];
        }

        // ---- inverse stage B' (intra-wave)
        #pragma unroll
        for (int k = 0; k < 16; ++k) {
            int s = swz(baseB0 + 16*k);
            xr[REV(k)] = re[s]; xi[REV(k)] = im[s];
        }
        twiddle_rev(xr, xi, -angB);
        idft16(xr, xi);
        #pragma unroll
        for (int n = 0; n < 16; ++n) {
            int s = swz(baseB0 + 16*n);
            re[s] = xr[n]; im[s] = xi[n];
        }
        __syncthreads();   // barrier2: W(B') ready for A' (drains DMA vmcnt)

        // ---- inverse stage A'
        #pragma unroll
        for (int k = 0; k < 16; ++k) {
            int s = swz(t + 256*k);
            xr[REV(k)] = re[s]; xi[REV(k)] = im[s];
        }
        twiddle_rev(xr, xi, -angA);
        idft16(xr, xi);
        __syncthreads();   // barrier3: all A'-reads done; W free, S data visible

        // ---- epilogue stores (overlap next iteration's stage A)
        {
            float* o0 = out + pair * (2LL * FFT_N);
            #pragma unroll
            for (int n = 0; n < 16; ++n) {
                int i = t + 256*n;
                float l = lw[i];
                o0[i]         = fmaxf(xr[n]*l, 0.0f);
                o0[FFT_N + i] = fmaxf(xi[n]*l, 0.0f);
            }
        }
        pair += GRID;
    }
}

extern "C" void kernel_launch(void* const* d_in, const int* in_sizes, int n_in,
                              void* d_out, int out_size, void* d_ws, size_t ws_size,
                              hipStream_t stream) {
    const float* inputs = (const float*)d_in[0];
    const float* fw     = (const float*)d_in[1];
    const float* lw     = (const float*)d_in[2];
    float* out   = (float*)d_out;
    float* gperm = (float*)d_ws;   // 4096 floats = 16 KB scratch

    hipLaunchKernelGGL(setup_g_kernel, dim3(FFT_N / THREADS), dim3(THREADS), 0, stream,
                       fw, gperm);

    hipLaunchKernelGGL(fourier_fft_kernel, dim3(GRID), dim3(THREADS), 0, stream,
                       inputs, gperm, lw, out);
}

// Round 17
// 130.789 us; speedup vs baseline: 1.3114x; 1.2817x over previous
//
#include <hip/hip_runtime.h>
#include <math.h>

#define FFT_N   4096
#define THREADS 256
#define PADC    4384   // complex slots after 3-term pad (max index 4377)

// R17: single interleaved LDS array, complex slot p -> floats sh[2p](re),
// sh[2p+1](im). Pad p(i) = i + 4*(i>>6) + 2*(i>>8) (R10-proven uniform):
//  A (i=t+256k):    p = [t+4*(t>>6)] + 274k          (linear -> imm offsets)
//  B (i=256a+j+16k):p = [274a+j] + 16k+4*(k>>2)      (linear -> imm offsets)
//  C (i=16t+n):     p = [16t+4*(t>>2)+2*(t>>4)] + n  (contiguous, 16B-aligned)
// re/im written as ADJACENT SCALAR accesses (sh[2s], sh[2s+1]) so the
// backend can merge them into ds_read2_b32/ds_write2_b32 (independent
// registers - no float2 pairing cost, half the LDS instructions).
// Bank check (paired b32): stage A banks (2t)&31 -> 4 lanes/bank exactly;
// stage B (4a+2j)&31 -> 4 lanes/bank exactly; stage C float4 quad-groups
// 8 lanes each. All minimum-conflict (free).

#define REV(r) ((((r) & 3) << 2) | ((r) >> 2))

// gperm[16t + r] = G at local position 16t + REV(r),
// G(p) = ((W[k]+W[(N-k)%N])/2 + 1)/N, k = 3-digit base-16 reversal of p.
__global__ void setup_g_kernel(const float* __restrict__ fw, float* __restrict__ gperm) {
    int p = blockIdx.x * blockDim.x + threadIdx.x;
    if (p >= FFT_N) return;
    int r = p & 15;
    int local = (p & ~15) | REV(r);
    unsigned k = ((local & 15u) << 8) | ((unsigned)local & 0xF0u) | ((unsigned)local >> 8);
    float wk  = fw[k];
    float wnk = fw[(FFT_N - k) & (FFT_N - 1)];
    gperm[p] = (0.5f * (wk + wnk) + 1.0f) * (1.0f / (float)FFT_N);
}

__device__ __forceinline__ void cmul(float& xr, float& xi, float c, float s) {
    float tv = xr; xr = tv * c - xi * s; xi = tv * s + xi * c;
}

__device__ __forceinline__ void bfly4_f(float& ar, float& ai, float& br, float& bi,
                                        float& cr, float& ci, float& dr, float& di) {
    float t0r = ar + cr, t0i = ai + ci;
    float t1r = ar - cr, t1i = ai - ci;
    float t2r = br + dr, t2i = bi + di;
    float t3r = br - dr, t3i = bi - di;
    ar = t0r + t2r; ai = t0i + t2i;
    br = t1r + t3i; bi = t1i - t3r;
    cr = t0r - t2r; ci = t0i - t2i;
    dr = t1r - t3i; di = t1i + t3r;
}
__device__ __forceinline__ void bfly4_i(float& ar, float& ai, float& br, float& bi,
                                        float& cr, float& ci, float& dr, float& di) {
    float t0r = ar + cr, t0i = ai + ci;
    float t1r = ar - cr, t1i = ai - ci;
    float t2r = br + dr, t2i = bi + di;
    float t3r = br - dr, t3i = bi - di;
    ar = t0r + t2r; ai = t0i + t2i;
    br = t1r - t3i; bi = t1i + t3r;
    cr = t0r - t2r; ci = t0i - t2i;
    dr = t1r + t3i; di = t1i - t3r;
}

// In-place forward DFT16 (DIF). Output: slot r holds X[REV(r)].
__device__ __forceinline__ void dft16_f(float xr[16], float xi[16]) {
    const float C1 = 0.9238795325112867f;
    const float S1 = 0.3826834323650898f;
    const float H  = 0.7071067811865476f;
    #pragma unroll
    for (int m = 0; m < 4; ++m)
        bfly4_f(xr[m],xi[m], xr[m+4],xi[m+4], xr[m+8],xi[m+8], xr[m+12],xi[m+12]);
    cmul(xr[5],  xi[5],   C1, -S1);
    cmul(xr[9],  xi[9],    H,  -H);
    cmul(xr[13], xi[13],  S1, -C1);
    cmul(xr[6],  xi[6],    H,  -H);
    cmul(xr[10], xi[10], 0.f, -1.f);
    cmul(xr[14], xi[14],  -H,  -H);
    cmul(xr[7],  xi[7],   S1, -C1);
    cmul(xr[11], xi[11],  -H,  -H);
    cmul(xr[15], xi[15], -C1,  S1);
    #pragma unroll
    for (int g = 0; g < 4; ++g)
        bfly4_f(xr[4*g],xi[4*g], xr[4*g+1],xi[4*g+1], xr[4*g+2],xi[4*g+2], xr[4*g+3],xi[4*g+3]);
}

// In-place inverse DFT16 (unnormalized). Input: slot r holds X[REV(r)].
__device__ __forceinline__ void idft16(float xr[16], float xi[16]) {
    const float C1 = 0.9238795325112867f;
    const float S1 = 0.3826834323650898f;
    const float H  = 0.7071067811865476f;
    #pragma unroll
    for (int g = 0; g < 4; ++g)
        bfly4_i(xr[4*g],xi[4*g], xr[4*g+1],xi[4*g+1], xr[4*g+2],xi[4*g+2], xr[4*g+3],xi[4*g+3]);
    cmul(xr[5],  xi[5],   C1,  S1);
    cmul(xr[9],  xi[9],    H,   H);
    cmul(xr[13], xi[13],  S1,  C1);
    cmul(xr[6],  xi[6],    H,   H);
    cmul(xr[10], xi[10], 0.f, 1.f);
    cmul(xr[14], xi[14],  -H,   H);
    cmul(xr[7],  xi[7],   S1,  C1);
    cmul(xr[11], xi[11],  -H,   H);
    cmul(xr[15], xi[15], -C1, -S1);
    #pragma unroll
    for (int m = 0; m < 4; ++m)
        bfly4_i(xr[m],xi[m], xr[m+4],xi[m+4], xr[m+8],xi[m+8], xr[m+12],xi[m+12]);
}

// apply w^{REV(r)} to slot r; binary-power chain, dependency depth ~5.
__device__ __forceinline__ void twiddle_rev(float xr[16], float xi[16], float ang) {
    float s1, c1; __sincosf(ang, &s1, &c1);
    float c2 = c1*c1 - s1*s1, s2 = 2.f*c1*s1;
    float c3 = c2*c1 - s2*s1, s3 = c2*s1 + s2*c1;
    float c4 = c2*c2 - s2*s2, s4 = 2.f*c2*s2;
    cmul(xr[4],  xi[4],  c1, s1);
    cmul(xr[8],  xi[8],  c2, s2);
    cmul(xr[12], xi[12], c3, s3);
    float bc = c4, bs = s4;
    #pragma unroll
    for (int q = 1; q < 4; ++q) {
        cmul(xr[q], xi[q], bc, bs);
        { float ec = bc*c1 - bs*s1, es = bc*s1 + bs*c1; cmul(xr[4+q],  xi[4+q],  ec, es); }
        { float ec = bc*c2 - bs*s2, es = bc*s2 + bs*c2; cmul(xr[8+q],  xi[8+q],  ec, es); }
        { float ec = bc*c3 - bs*s3, es = bc*s3 + bs*c3; cmul(xr[12+q], xi[12+q], ec, es); }
        if (q < 3) { float nb = bc*c4 - bs*s4; bs = bc*s4 + bs*c4; bc = nb; }
    }
}

__global__ __launch_bounds__(THREADS, 4) void fourier_fft_kernel(
    const float* __restrict__ in, const float* __restrict__ gperm,
    const float* __restrict__ lw, float* __restrict__ out)
{
    __shared__ __align__(16) float sh[2 * PADC];
    const int t = threadIdx.x;
    const long long pair = blockIdx.x;
    const float* r0 = in + pair * (2LL * FFT_N);
    const float* r1 = r0 + FFT_N;

    const float CFA = -6.28318530717958647692f / 4096.0f;
    const float CFB = -6.28318530717958647692f / 256.0f;

    // per-thread complex-slot bases (all per-k offsets compile-time)
    const int baseA = t + 4 * (t >> 6);                        // + 274k
    const int baseB = 274 * (t >> 4) + (t & 15);               // + 16k + 4*(k>>2)
    const int baseC = 16 * t + 4 * (t >> 2) + 2 * (t >> 4);    // + n (even -> 16B-aligned)
    const int jb = t & 15;

    float xr[16], xi[16];

    // load: thread t owns x[t + 256n] — coalesced
    #pragma unroll
    for (int n = 0; n < 16; ++n) {
        xr[n] = r0[t + 256*n];
        xi[n] = r1[t + 256*n];
    }

    // ---- forward stage A (L=4096, j=t): slot r holds A[REV(r)]
    dft16_f(xr, xi);
    twiddle_rev(xr, xi, CFA * (float)t);
    #pragma unroll
    for (int k = 0; k < 16; ++k) {
        int f = 2 * (baseA + 274*k);
        sh[f]     = xr[REV(k)];
        sh[f + 1] = xi[REV(k)];
    }
    __syncthreads();

    // ---- forward stage B (L=256, j=t&15)
    #pragma unroll
    for (int n = 0; n < 16; ++n) {
        int f = 2 * (baseB + 16*n + 4*(n>>2));
        xr[n] = sh[f]; xi[n] = sh[f + 1];
    }
    dft16_f(xr, xi);
    twiddle_rev(xr, xi, CFB * (float)jb);
    #pragma unroll
    for (int k = 0; k < 16; ++k) {
        int f = 2 * (baseB + 16*k + 4*(k>>2));
        sh[f]     = xr[REV(k)];
        sh[f + 1] = xi[REV(k)];
    }
    __syncthreads();

    // ---- forward stage C + pointwise G + inverse stage C' (registers; b128 LDS)
    #pragma unroll
    for (int q = 0; q < 8; ++q) {
        float4 v = *(const float4*)&sh[2 * (baseC + 2*q)];
        xr[2*q+0] = v.x; xi[2*q+0] = v.y;
        xr[2*q+1] = v.z; xi[2*q+1] = v.w;
    }
    dft16_f(xr, xi);
    {
        const float4* gp = (const float4*)(gperm + 16*t);   // already REV-permuted
        #pragma unroll
        for (int q = 0; q < 4; ++q) {
            float4 g = gp[q];
            xr[4*q+0] *= g.x; xi[4*q+0] *= g.x;
            xr[4*q+1] *= g.y; xi[4*q+1] *= g.y;
            xr[4*q+2] *= g.z; xi[4*q+2] *= g.z;
            xr[4*q+3] *= g.w; xi[4*q+3] *= g.w;
        }
    }
    idft16(xr, xi);
    #pragma unroll
    for (int q = 0; q < 8; ++q) {
        *(float4*)&sh[2 * (baseC + 2*q)] =
            make_float4(xr[2*q+0], xi[2*q+0], xr[2*q+1], xi[2*q+1]);
    }
    __syncthreads();

    // ---- inverse stage B': load digit-reversed, conj twiddle, idft16
    #pragma unroll
    for (int k = 0; k < 16; ++k) {
        int f = 2 * (baseB + 16*k + 4*(k>>2));
        xr[REV(k)] = sh[f]; xi[REV(k)] = sh[f + 1];
    }
    twiddle_rev(xr, xi, -CFB * (float)jb);
    idft16(xr, xi);
    #pragma unroll
    for (int n = 0; n < 16; ++n) {
        int f = 2 * (baseB + 16*n + 4*(n>>2));
        sh[f]     = xr[n];
        sh[f + 1] = xi[n];
    }
    __syncthreads();

    // ---- inverse stage A' + epilogue straight from registers
    #pragma unroll
    for (int k = 0; k < 16; ++k) {
        int f = 2 * (baseA + 274*k);
        xr[REV(k)] = sh[f]; xi[REV(k)] = sh[f + 1];
    }
    twiddle_rev(xr, xi, -CFA * (float)t);
    idft16(xr, xi);

    float* o0 = out + pair * (2LL * FFT_N);
    #pragma unroll
    for (int n = 0; n < 16; ++n) {
        int i = t + 256*n;
        float l = lw[i];
        o0[i]         = fmaxf(xr[n]*l, 0.0f);
        o0[FFT_N + i] = fmaxf(xi[n]*l, 0.0f);
    }
}

extern "C" void kernel_launch(void* const* d_in, const int* in_sizes, int n_in,
                              void* d_out, int out_size, void* d_ws, size_t ws_size,
                              hipStream_t stream) {
    const float* inputs = (const float*)d_in[0];
    const float* fw     = (const float*)d_in[1];
    const float* lw     = (const float*)d_in[2];
    float* out   = (float*)d_out;
    float* gperm = (float*)d_ws;   // 4096 floats = 16 KB scratch

    hipLaunchKernelGGL(setup_g_kernel, dim3(FFT_N / THREADS), dim3(THREADS), 0, stream,
                       fw, gperm);

    const int pairs = in_sizes[0] / (2 * FFT_N);   // 16384 rows -> 8192 pairs
    hipLaunchKernelGGL(fourier_fft_kernel, dim3(pairs), dim3(THREADS), 0, stream,
                       inputs, gperm, lw, out);
}